// Round 1
// baseline (788.867 us; speedup 1.0000x reference)
//
#include <hip/hip_runtime.h>

#define QN 512
#define DN 1024
#define BN 64
#define LN 1024

typedef _Float16 f16x8 __attribute__((ext_vector_type(8)));
typedef _Float16 f16x4 __attribute__((ext_vector_type(4)));
typedef float f32x4 __attribute__((ext_vector_type(4)));

// ---------------- kernel 1a: tokens fp32 -> f16 natural [b][l][d] + transposed [b][d][l]
__global__ __launch_bounds__(256) void k_convert(const float* __restrict__ tok,
                                                 _Float16* __restrict__ T,
                                                 _Float16* __restrict__ TT) {
  __shared__ __align__(16) _Float16 tile[64][68];  // [d][l], +4 pad keeps 8B align & breaks conflicts
  const int b = blockIdx.z;
  const int l0 = blockIdx.y * 64, d0 = blockIdx.x * 64;
  const int tid = threadIdx.x;
  const int rr = tid >> 4;  // 0..15
  const int cq = tid & 15;  // group of 4
  const size_t base = (size_t)b * LN * DN;
#pragma unroll
  for (int p = 0; p < 4; ++p) {
    const int l = p * 16 + rr;
    const float4 v = *(const float4*)(tok + base + (size_t)(l0 + l) * DN + d0 + cq * 4);
    f16x4 hv;
    hv[0] = (_Float16)v.x; hv[1] = (_Float16)v.y; hv[2] = (_Float16)v.z; hv[3] = (_Float16)v.w;
    *(f16x4*)(T + base + (size_t)(l0 + l) * DN + d0 + cq * 4) = hv;
    tile[cq * 4 + 0][l] = hv[0];
    tile[cq * 4 + 1][l] = hv[1];
    tile[cq * 4 + 2][l] = hv[2];
    tile[cq * 4 + 3][l] = hv[3];
  }
  __syncthreads();
  const size_t baseT = (size_t)b * DN * LN;
#pragma unroll
  for (int p = 0; p < 4; ++p) {
    const int d = p * 16 + rr;
    const f16x4 hv = *(const f16x4*)(&tile[d][cq * 4]);
    *(f16x4*)(TT + baseT + (size_t)(d0 + d) * LN + l0 + cq * 4) = hv;
  }
}

// ---------------- kernel 1b: queries fp32 -> f16 + 1/max(||q||,eps)
__global__ __launch_bounds__(256) void k_queries(const float* __restrict__ q,
                                                 _Float16* __restrict__ Qh,
                                                 float* __restrict__ invqn) {
  const int qr = blockIdx.x;
  const int tid = threadIdx.x;
  const float4 v = *(const float4*)(q + (size_t)qr * DN + tid * 4);
  float ss = v.x * v.x + v.y * v.y + v.z * v.z + v.w * v.w;
#pragma unroll
  for (int off = 1; off < 64; off <<= 1) ss += __shfl_xor(ss, off, 64);
  __shared__ float red[4];
  if ((tid & 63) == 0) red[tid >> 6] = ss;
  __syncthreads();
  const float tot = red[0] + red[1] + red[2] + red[3];
  f16x4 hv;
  hv[0] = (_Float16)v.x; hv[1] = (_Float16)v.y; hv[2] = (_Float16)v.z; hv[3] = (_Float16)v.w;
  *(f16x4*)(Qh + (size_t)qr * DN + tid * 4) = hv;
  if (tid == 0) invqn[qr] = 1.0f / fmaxf(sqrtf(tot), 1e-12f);
}

// ---------------- kernel 2: scores + exact softmax + num + P (normalized attn, f16)
// block: (q-tile of 64) x (batch); 512 threads = 8 waves.
// wave w owns all 4 q subtiles x 8 l-tiles: l in [w*128, (w+1)*128)
__global__ __launch_bounds__(512, 2) void k_scores(const _Float16* __restrict__ Qh,
                                                   const _Float16* __restrict__ T,
                                                   _Float16* __restrict__ P,
                                                   float* __restrict__ numv) {
  __shared__ float maxbuf[8][64];
  __shared__ float sumbuf[8][64];
  __shared__ float numbuf[8][64];
  __shared__ float Mbuf[64];
  __shared__ float Rbuf[64];
  const int b = blockIdx.y;
  const int q0 = blockIdx.x * 64;
  const int tid = threadIdx.x;
  const int w = tid >> 6, lane = tid & 63, c = lane & 15, quad = lane >> 4;

  f32x4 acc[4][8];
#pragma unroll
  for (int i = 0; i < 4; ++i)
#pragma unroll
    for (int j = 0; j < 8; ++j) acc[i][j] = 0.f;

  const _Float16* __restrict__ Tb = T + (size_t)b * LN * DN;
  const _Float16* __restrict__ Ab = Qh + (size_t)q0 * DN;

  for (int ks2 = 0; ks2 < 16; ++ks2) {
    const int k0 = ks2 * 64 + quad * 8;
    f16x8 bfr[8][2];
#pragma unroll
    for (int lt = 0; lt < 8; ++lt) {
      const _Float16* p = Tb + (size_t)((w * 8 + lt) * 16 + c) * DN + k0;
      bfr[lt][0] = *(const f16x8*)p;
      bfr[lt][1] = *(const f16x8*)(p + 32);
    }
#pragma unroll
    for (int kk = 0; kk < 2; ++kk) {
      f16x8 afr[4];
#pragma unroll
      for (int qt = 0; qt < 4; ++qt)
        afr[qt] = *(const f16x8*)(Ab + (size_t)(qt * 16 + c) * DN + k0 + kk * 32);
#pragma unroll
      for (int qt = 0; qt < 4; ++qt)
#pragma unroll
        for (int lt = 0; lt < 8; ++lt)
          acc[qt][lt] = __builtin_amdgcn_mfma_f32_16x16x32_f16(afr[qt], bfr[lt][kk],
                                                               acc[qt][lt], 0, 0, 0);
    }
  }

  // acc[qt][lt][r] = u  at row q = qt*16+quad*4+r , col l = (w*8+lt)*16+c
  float mx[4][4];
#pragma unroll
  for (int qt = 0; qt < 4; ++qt)
#pragma unroll
    for (int r = 0; r < 4; ++r) {
      float m = acc[qt][0][r];
#pragma unroll
      for (int lt = 1; lt < 8; ++lt) m = fmaxf(m, acc[qt][lt][r]);
      mx[qt][r] = m;
    }
#pragma unroll
  for (int off = 1; off < 16; off <<= 1)
#pragma unroll
    for (int qt = 0; qt < 4; ++qt)
#pragma unroll
      for (int r = 0; r < 4; ++r) mx[qt][r] = fmaxf(mx[qt][r], __shfl_xor(mx[qt][r], off, 64));
  if (c == 0)
#pragma unroll
    for (int qt = 0; qt < 4; ++qt)
#pragma unroll
      for (int r = 0; r < 4; ++r) maxbuf[w][qt * 16 + quad * 4 + r] = mx[qt][r];
  __syncthreads();
  if (tid < 64) {
    float m = maxbuf[0][tid];
#pragma unroll
    for (int ww = 1; ww < 8; ++ww) m = fmaxf(m, maxbuf[ww][tid]);
    Mbuf[tid] = m;
  }
  __syncthreads();

  const float KE = 0.045084220027780106f;  // log2(e)/32  (scores = u/sqrt(1024))
  float Mr[4][4], sl[4][4], nl[4][4];
#pragma unroll
  for (int qt = 0; qt < 4; ++qt)
#pragma unroll
    for (int r = 0; r < 4; ++r) {
      Mr[qt][r] = Mbuf[qt * 16 + quad * 4 + r];
      sl[qt][r] = 0.f;
      nl[qt][r] = 0.f;
    }
#pragma unroll
  for (int qt = 0; qt < 4; ++qt)
#pragma unroll
    for (int lt = 0; lt < 8; ++lt)
#pragma unroll
      for (int r = 0; r < 4; ++r) {
        const float u = acc[qt][lt][r];
        const float p = exp2f((u - Mr[qt][r]) * KE);
        acc[qt][lt][r] = p;
        sl[qt][r] += p;
        nl[qt][r] += p * u;
      }
#pragma unroll
  for (int off = 1; off < 16; off <<= 1)
#pragma unroll
    for (int qt = 0; qt < 4; ++qt)
#pragma unroll
      for (int r = 0; r < 4; ++r) {
        sl[qt][r] += __shfl_xor(sl[qt][r], off, 64);
        nl[qt][r] += __shfl_xor(nl[qt][r], off, 64);
      }
  if (c == 0)
#pragma unroll
    for (int qt = 0; qt < 4; ++qt)
#pragma unroll
      for (int r = 0; r < 4; ++r) {
        sumbuf[w][qt * 16 + quad * 4 + r] = sl[qt][r];
        numbuf[w][qt * 16 + quad * 4 + r] = nl[qt][r];
      }
  __syncthreads();
  if (tid < 64) {
    float S = 0.f, N = 0.f;
#pragma unroll
    for (int ww = 0; ww < 8; ++ww) {
      S += sumbuf[ww][tid];
      N += numbuf[ww][tid];
    }
    Rbuf[tid] = 1.0f / S;
    numv[(size_t)b * QN + q0 + tid] = N / S;  // = q . agg  (exact fp32 ratio)
  }
  __syncthreads();

  _Float16* Pb = P + ((size_t)b * QN + q0) * LN;
#pragma unroll
  for (int qt = 0; qt < 4; ++qt)
#pragma unroll
    for (int r = 0; r < 4; ++r) {
      const int row = qt * 16 + quad * 4 + r;
      const float rS = Rbuf[row];
      _Float16* prow = Pb + (size_t)row * LN + c;
#pragma unroll
      for (int lt = 0; lt < 8; ++lt) prow[(w * 8 + lt) * 16] = (_Float16)(acc[qt][lt][r] * rS);
    }
}

// ---------------- kernel 3: agg = P @ T (via TT), reduce to ||agg||^2 per (b,q)
__global__ __launch_bounds__(512, 2) void k_agg(const _Float16* __restrict__ P,
                                                const _Float16* __restrict__ TT,
                                                float* __restrict__ norm2) {
  __shared__ float redbuf[8][64];
  const int b = blockIdx.y;
  const int q0 = blockIdx.x * 64;
  const int tid = threadIdx.x;
  const int w = tid >> 6, lane = tid & 63, c = lane & 15, quad = lane >> 4;

  f32x4 acc[4][8];
#pragma unroll
  for (int i = 0; i < 4; ++i)
#pragma unroll
    for (int j = 0; j < 8; ++j) acc[i][j] = 0.f;

  const _Float16* __restrict__ Tb = TT + (size_t)b * DN * LN;
  const _Float16* __restrict__ Pb = P + ((size_t)b * QN + q0) * LN;

  for (int ks2 = 0; ks2 < 16; ++ks2) {
    const int k0 = ks2 * 64 + quad * 8;  // k over l
    f16x8 bfr[8][2];
#pragma unroll
    for (int dt = 0; dt < 8; ++dt) {
      const _Float16* p = Tb + (size_t)((w * 8 + dt) * 16 + c) * LN + k0;
      bfr[dt][0] = *(const f16x8*)p;
      bfr[dt][1] = *(const f16x8*)(p + 32);
    }
#pragma unroll
    for (int kk = 0; kk < 2; ++kk) {
      f16x8 afr[4];
#pragma unroll
      for (int qt = 0; qt < 4; ++qt)
        afr[qt] = *(const f16x8*)(Pb + (size_t)(qt * 16 + c) * LN + k0 + kk * 32);
#pragma unroll
      for (int qt = 0; qt < 4; ++qt)
#pragma unroll
        for (int dt = 0; dt < 8; ++dt)
          acc[qt][dt] = __builtin_amdgcn_mfma_f32_16x16x32_f16(afr[qt], bfr[dt][kk],
                                                               acc[qt][dt], 0, 0, 0);
    }
  }

  float ss[4][4];
#pragma unroll
  for (int qt = 0; qt < 4; ++qt)
#pragma unroll
    for (int r = 0; r < 4; ++r) {
      float s = 0.f;
#pragma unroll
      for (int dt = 0; dt < 8; ++dt) {
        const float v = acc[qt][dt][r];
        s += v * v;
      }
      ss[qt][r] = s;
    }
#pragma unroll
  for (int off = 1; off < 16; off <<= 1)
#pragma unroll
    for (int qt = 0; qt < 4; ++qt)
#pragma unroll
      for (int r = 0; r < 4; ++r) ss[qt][r] += __shfl_xor(ss[qt][r], off, 64);
  if (c == 0)
#pragma unroll
    for (int qt = 0; qt < 4; ++qt)
#pragma unroll
      for (int r = 0; r < 4; ++r) redbuf[w][qt * 16 + quad * 4 + r] = ss[qt][r];
  __syncthreads();
  if (tid < 64) {
    float s = 0.f;
#pragma unroll
    for (int ww = 0; ww < 8; ++ww) s += redbuf[ww][tid];
    norm2[(size_t)b * QN + q0 + tid] = s;
  }
}

// ---------------- kernel 4: logits[q][b] = num * invqn / max(||agg||, eps)
__global__ __launch_bounds__(256) void k_final(const float* __restrict__ numv,
                                               const float* __restrict__ norm2,
                                               const float* __restrict__ invqn,
                                               float* __restrict__ out) {
  const int idx = blockIdx.x * 256 + threadIdx.x;  // 0..32767
  const int q = idx >> 6, b = idx & 63;
  const float n = numv[(size_t)b * QN + q];
  const float d = sqrtf(norm2[(size_t)b * QN + q]);
  out[idx] = n * invqn[q] / fmaxf(d, 1e-12f);
}

extern "C" void kernel_launch(void* const* d_in, const int* in_sizes, int n_in,
                              void* d_out, int out_size, void* d_ws, size_t ws_size,
                              hipStream_t stream) {
  (void)in_sizes; (void)n_in; (void)out_size; (void)ws_size;
  const float* queries = (const float*)d_in[0];
  const float* tok = (const float*)d_in[1];
  float* out = (float*)d_out;
  char* ws = (char*)d_ws;

  // workspace layout (bytes)
  _Float16* TT = (_Float16*)(ws + 0);           // 64*1024*1024*2 = 128 MB  [b][d][l]
  _Float16* T = (_Float16*)(ws + 134217728);    // 128 MB                   [b][l][d]
  _Float16* P = (_Float16*)(ws + 268435456);    // 64 MB                    [b][q][l]
  _Float16* Qh = (_Float16*)(ws + 335544320);   // 1 MB                     [q][d]
  float* invqn = (float*)(ws + 336592896);      // 2 KB
  float* numv = (float*)(ws + 336594944);       // 128 KB                   [b][q]
  float* norm2 = (float*)(ws + 336726016);      // 128 KB                   [b][q]

  hipLaunchKernelGGL(k_convert, dim3(16, 16, 64), dim3(256), 0, stream, tok, T, TT);
  hipLaunchKernelGGL(k_queries, dim3(512), dim3(256), 0, stream, queries, Qh, invqn);
  hipLaunchKernelGGL(k_scores, dim3(8, 64), dim3(512), 0, stream, Qh, T, P, numv);
  hipLaunchKernelGGL(k_agg, dim3(8, 64), dim3(512), 0, stream, P, TT, norm2);
  hipLaunchKernelGGL(k_final, dim3(128), dim3(256), 0, stream, numv, norm2, invqn, out);
}

// Round 2
// 781.092 us; speedup vs baseline: 1.0100x; 1.0100x over previous
//
#include <hip/hip_runtime.h>

#define QN 512
#define DN 1024
#define BN 64
#define LN 1024

typedef _Float16 f16x8 __attribute__((ext_vector_type(8)));
typedef _Float16 f16x4 __attribute__((ext_vector_type(4)));
typedef float f32x4 __attribute__((ext_vector_type(4)));

// ---------------- kernel 1a: tokens fp32 -> f16 natural [b][l][d] + transposed [b][d][l]
__global__ __launch_bounds__(256) void k_convert(const float* __restrict__ tok,
                                                 _Float16* __restrict__ T,
                                                 _Float16* __restrict__ TT) {
  __shared__ __align__(16) _Float16 tile[64][68];
  const int b = blockIdx.z;
  const int l0 = blockIdx.y * 64, d0 = blockIdx.x * 64;
  const int tid = threadIdx.x;
  const int rr = tid >> 4;
  const int cq = tid & 15;
  const size_t base = (size_t)b * LN * DN;
#pragma unroll
  for (int p = 0; p < 4; ++p) {
    const int l = p * 16 + rr;
    const float4 v = *(const float4*)(tok + base + (size_t)(l0 + l) * DN + d0 + cq * 4);
    f16x4 hv;
    hv[0] = (_Float16)v.x; hv[1] = (_Float16)v.y; hv[2] = (_Float16)v.z; hv[3] = (_Float16)v.w;
    *(f16x4*)(T + base + (size_t)(l0 + l) * DN + d0 + cq * 4) = hv;
    tile[cq * 4 + 0][l] = hv[0];
    tile[cq * 4 + 1][l] = hv[1];
    tile[cq * 4 + 2][l] = hv[2];
    tile[cq * 4 + 3][l] = hv[3];
  }
  __syncthreads();
  const size_t baseT = (size_t)b * DN * LN;
#pragma unroll
  for (int p = 0; p < 4; ++p) {
    const int d = p * 16 + rr;
    const f16x4 hv = *(const f16x4*)(&tile[d][cq * 4]);
    *(f16x4*)(TT + baseT + (size_t)(d0 + d) * LN + l0 + cq * 4) = hv;
  }
}

// ---------------- kernel 1b: queries fp32 -> f16 + 1/max(||q||,eps)
__global__ __launch_bounds__(256) void k_queries(const float* __restrict__ q,
                                                 _Float16* __restrict__ Qh,
                                                 float* __restrict__ invqn) {
  const int qr = blockIdx.x;
  const int tid = threadIdx.x;
  const float4 v = *(const float4*)(q + (size_t)qr * DN + tid * 4);
  float ss = v.x * v.x + v.y * v.y + v.z * v.z + v.w * v.w;
#pragma unroll
  for (int off = 1; off < 64; off <<= 1) ss += __shfl_xor(ss, off, 64);
  __shared__ float red[4];
  if ((tid & 63) == 0) red[tid >> 6] = ss;
  __syncthreads();
  const float tot = red[0] + red[1] + red[2] + red[3];
  f16x4 hv;
  hv[0] = (_Float16)v.x; hv[1] = (_Float16)v.y; hv[2] = (_Float16)v.z; hv[3] = (_Float16)v.w;
  *(f16x4*)(Qh + (size_t)qr * DN + tid * 4) = hv;
  if (tid == 0) invqn[qr] = 1.0f / fmaxf(sqrtf(tot), 1e-12f);
}

// XCD-locality decode: all 8 q-tile blocks of a given b get linear index
// i == b (mod 8) -> same XCD (round-robin dispatch heuristic). The 8
// identical blocks stream T[b] in lockstep; T[b] (2MB) is HBM-fetched once
// per XCD and re-served from the 4MB XCD L2.
__device__ __forceinline__ void decode_bq(int g, int& b, int& q0) {
  const int xcd = g & 7;
  const int t = g >> 3;
  const int qt8 = t & 7;
  b = ((t >> 3) << 3) | xcd;
  q0 = qt8 * 64;
}

// ---------------- kernel 2: scores + exact softmax + num + P (normalized attn, f16)
__global__ __launch_bounds__(512, 2) void k_scores(const _Float16* __restrict__ Qh,
                                                   const _Float16* __restrict__ T,
                                                   _Float16* __restrict__ P,
                                                   float* __restrict__ numv) {
  __shared__ float maxbuf[8][64];
  __shared__ float sumbuf[8][64];
  __shared__ float numbuf[8][64];
  __shared__ float Mbuf[64];
  __shared__ float Rbuf[64];
  int b, q0;
  decode_bq(blockIdx.x, b, q0);
  const int tid = threadIdx.x;
  const int w = tid >> 6, lane = tid & 63, c = lane & 15, quad = lane >> 4;

  f32x4 acc[4][8];
#pragma unroll
  for (int i = 0; i < 4; ++i)
#pragma unroll
    for (int j = 0; j < 8; ++j) acc[i][j] = 0.f;

  const _Float16* __restrict__ Tb = T + (size_t)b * LN * DN;
  const _Float16* __restrict__ Ab = Qh + (size_t)q0 * DN;

  for (int ks2 = 0; ks2 < 16; ++ks2) {
    const int k0 = ks2 * 64 + quad * 8;
    f16x8 bfr[8][2];
#pragma unroll
    for (int lt = 0; lt < 8; ++lt) {
      const _Float16* p = Tb + (size_t)((w * 8 + lt) * 16 + c) * DN + k0;
      bfr[lt][0] = *(const f16x8*)p;
      bfr[lt][1] = *(const f16x8*)(p + 32);
    }
#pragma unroll
    for (int kk = 0; kk < 2; ++kk) {
      f16x8 afr[4];
#pragma unroll
      for (int qt = 0; qt < 4; ++qt)
        afr[qt] = *(const f16x8*)(Ab + (size_t)(qt * 16 + c) * DN + k0 + kk * 32);
#pragma unroll
      for (int qt = 0; qt < 4; ++qt)
#pragma unroll
        for (int lt = 0; lt < 8; ++lt)
          acc[qt][lt] = __builtin_amdgcn_mfma_f32_16x16x32_f16(afr[qt], bfr[lt][kk],
                                                               acc[qt][lt], 0, 0, 0);
    }
  }

  // acc[qt][lt][r] = u  at row q = qt*16+quad*4+r , col l = (w*8+lt)*16+c
  float mx[4][4];
#pragma unroll
  for (int qt = 0; qt < 4; ++qt)
#pragma unroll
    for (int r = 0; r < 4; ++r) {
      float m = acc[qt][0][r];
#pragma unroll
      for (int lt = 1; lt < 8; ++lt) m = fmaxf(m, acc[qt][lt][r]);
      mx[qt][r] = m;
    }
#pragma unroll
  for (int off = 1; off < 16; off <<= 1)
#pragma unroll
    for (int qt = 0; qt < 4; ++qt)
#pragma unroll
      for (int r = 0; r < 4; ++r) mx[qt][r] = fmaxf(mx[qt][r], __shfl_xor(mx[qt][r], off, 64));
  if (c == 0)
#pragma unroll
    for (int qt = 0; qt < 4; ++qt)
#pragma unroll
      for (int r = 0; r < 4; ++r) maxbuf[w][qt * 16 + quad * 4 + r] = mx[qt][r];
  __syncthreads();
  if (tid < 64) {
    float m = maxbuf[0][tid];
#pragma unroll
    for (int ww = 1; ww < 8; ++ww) m = fmaxf(m, maxbuf[ww][tid]);
    Mbuf[tid] = m;
  }
  __syncthreads();

  const float KE = 0.045084220027780106f;  // log2(e)/32  (scores = u/sqrt(1024))
  float Mr[4][4], sl[4][4], nl[4][4];
#pragma unroll
  for (int qt = 0; qt < 4; ++qt)
#pragma unroll
    for (int r = 0; r < 4; ++r) {
      Mr[qt][r] = Mbuf[qt * 16 + quad * 4 + r];
      sl[qt][r] = 0.f;
      nl[qt][r] = 0.f;
    }
#pragma unroll
  for (int qt = 0; qt < 4; ++qt)
#pragma unroll
    for (int lt = 0; lt < 8; ++lt)
#pragma unroll
      for (int r = 0; r < 4; ++r) {
        const float u = acc[qt][lt][r];
        const float p = exp2f((u - Mr[qt][r]) * KE);
        acc[qt][lt][r] = p;
        sl[qt][r] += p;
        nl[qt][r] += p * u;
      }
#pragma unroll
  for (int off = 1; off < 16; off <<= 1)
#pragma unroll
    for (int qt = 0; qt < 4; ++qt)
#pragma unroll
      for (int r = 0; r < 4; ++r) {
        sl[qt][r] += __shfl_xor(sl[qt][r], off, 64);
        nl[qt][r] += __shfl_xor(nl[qt][r], off, 64);
      }
  if (c == 0)
#pragma unroll
    for (int qt = 0; qt < 4; ++qt)
#pragma unroll
      for (int r = 0; r < 4; ++r) {
        sumbuf[w][qt * 16 + quad * 4 + r] = sl[qt][r];
        numbuf[w][qt * 16 + quad * 4 + r] = nl[qt][r];
      }
  __syncthreads();
  if (tid < 64) {
    float S = 0.f, N = 0.f;
#pragma unroll
    for (int ww = 0; ww < 8; ++ww) {
      S += sumbuf[ww][tid];
      N += numbuf[ww][tid];
    }
    Rbuf[tid] = 1.0f / S;
    numv[(size_t)b * QN + q0 + tid] = N / S;  // = q . agg  (exact fp32 ratio)
  }
  __syncthreads();

  _Float16* Pb = P + ((size_t)b * QN + q0) * LN;
#pragma unroll
  for (int qt = 0; qt < 4; ++qt)
#pragma unroll
    for (int r = 0; r < 4; ++r) {
      const int row = qt * 16 + quad * 4 + r;
      const float rS = Rbuf[row];
      _Float16* prow = Pb + (size_t)row * LN + c;
#pragma unroll
      for (int lt = 0; lt < 8; ++lt) prow[(w * 8 + lt) * 16] = (_Float16)(acc[qt][lt][r] * rS);
    }
}

// ---------------- kernel 3: agg = P @ T (via TT), reduce to ||agg||^2 per (b,q)
__global__ __launch_bounds__(512, 2) void k_agg(const _Float16* __restrict__ P,
                                                const _Float16* __restrict__ TT,
                                                float* __restrict__ norm2) {
  __shared__ float redbuf[8][64];
  int b, q0;
  decode_bq(blockIdx.x, b, q0);
  const int tid = threadIdx.x;
  const int w = tid >> 6, lane = tid & 63, c = lane & 15, quad = lane >> 4;

  f32x4 acc[4][8];
#pragma unroll
  for (int i = 0; i < 4; ++i)
#pragma unroll
    for (int j = 0; j < 8; ++j) acc[i][j] = 0.f;

  const _Float16* __restrict__ Tb = TT + (size_t)b * DN * LN;
  const _Float16* __restrict__ Pb = P + ((size_t)b * QN + q0) * LN;

  for (int ks2 = 0; ks2 < 16; ++ks2) {
    const int k0 = ks2 * 64 + quad * 8;  // k over l
    f16x8 bfr[8][2];
#pragma unroll
    for (int dt = 0; dt < 8; ++dt) {
      const _Float16* p = Tb + (size_t)((w * 8 + dt) * 16 + c) * LN + k0;
      bfr[dt][0] = *(const f16x8*)p;
      bfr[dt][1] = *(const f16x8*)(p + 32);
    }
#pragma unroll
    for (int kk = 0; kk < 2; ++kk) {
      f16x8 afr[4];
#pragma unroll
      for (int qt = 0; qt < 4; ++qt)
        afr[qt] = *(const f16x8*)(Pb + (size_t)(qt * 16 + c) * LN + k0 + kk * 32);
#pragma unroll
      for (int qt = 0; qt < 4; ++qt)
#pragma unroll
        for (int dt = 0; dt < 8; ++dt)
          acc[qt][dt] = __builtin_amdgcn_mfma_f32_16x16x32_f16(afr[qt], bfr[dt][kk],
                                                               acc[qt][dt], 0, 0, 0);
    }
  }

  float ss[4][4];
#pragma unroll
  for (int qt = 0; qt < 4; ++qt)
#pragma unroll
    for (int r = 0; r < 4; ++r) {
      float s = 0.f;
#pragma unroll
      for (int dt = 0; dt < 8; ++dt) {
        const float v = acc[qt][dt][r];
        s += v * v;
      }
      ss[qt][r] = s;
    }
#pragma unroll
  for (int off = 1; off < 16; off <<= 1)
#pragma unroll
    for (int qt = 0; qt < 4; ++qt)
#pragma unroll
      for (int r = 0; r < 4; ++r) ss[qt][r] += __shfl_xor(ss[qt][r], off, 64);
  if (c == 0)
#pragma unroll
    for (int qt = 0; qt < 4; ++qt)
#pragma unroll
      for (int r = 0; r < 4; ++r) redbuf[w][qt * 16 + quad * 4 + r] = ss[qt][r];
  __syncthreads();
  if (tid < 64) {
    float s = 0.f;
#pragma unroll
    for (int ww = 0; ww < 8; ++ww) s += redbuf[ww][tid];
    norm2[(size_t)b * QN + q0 + tid] = s;
  }
}

// ---------------- kernel 4: logits[q][b] = num * invqn / max(||agg||, eps)
__global__ __launch_bounds__(256) void k_final(const float* __restrict__ numv,
                                               const float* __restrict__ norm2,
                                               const float* __restrict__ invqn,
                                               float* __restrict__ out) {
  const int idx = blockIdx.x * 256 + threadIdx.x;  // 0..32767
  const int q = idx >> 6, b = idx & 63;
  const float n = numv[(size_t)b * QN + q];
  const float d = sqrtf(norm2[(size_t)b * QN + q]);
  out[idx] = n * invqn[q] / fmaxf(d, 1e-12f);
}

extern "C" void kernel_launch(void* const* d_in, const int* in_sizes, int n_in,
                              void* d_out, int out_size, void* d_ws, size_t ws_size,
                              hipStream_t stream) {
  (void)in_sizes; (void)n_in; (void)out_size; (void)ws_size;
  const float* queries = (const float*)d_in[0];
  const float* tok = (const float*)d_in[1];
  float* out = (float*)d_out;
  char* ws = (char*)d_ws;

  // workspace layout (bytes)
  _Float16* TT = (_Float16*)(ws + 0);           // 128 MB  [b][d][l]
  _Float16* T = (_Float16*)(ws + 134217728);    // 128 MB  [b][l][d]
  _Float16* P = (_Float16*)(ws + 268435456);    // 64 MB   [b][q][l]
  _Float16* Qh = (_Float16*)(ws + 335544320);   // 1 MB    [q][d]
  float* invqn = (float*)(ws + 336592896);      // 2 KB
  float* numv = (float*)(ws + 336594944);       // 128 KB  [b][q]
  float* norm2 = (float*)(ws + 336726016);      // 128 KB  [b][q]

  hipLaunchKernelGGL(k_convert, dim3(16, 16, 64), dim3(256), 0, stream, tok, T, TT);
  hipLaunchKernelGGL(k_queries, dim3(512), dim3(256), 0, stream, queries, Qh, invqn);
  hipLaunchKernelGGL(k_scores, dim3(512), dim3(512), 0, stream, Qh, T, P, numv);
  hipLaunchKernelGGL(k_agg, dim3(512), dim3(512), 0, stream, P, TT, norm2);
  hipLaunchKernelGGL(k_final, dim3(128), dim3(256), 0, stream, numv, norm2, invqn, out);
}

// Round 4
// 702.299 us; speedup vs baseline: 1.1233x; 1.1122x over previous
//
#include <hip/hip_runtime.h>
#include <stdint.h>

#define QN 512
#define DN 1024
#define BN 64
#define LN 1024

typedef _Float16 f16x8 __attribute__((ext_vector_type(8)));
typedef _Float16 f16x4 __attribute__((ext_vector_type(4)));
typedef float f32x4 __attribute__((ext_vector_type(4)));

// async global->LDS DMA, 16B per lane, lane-linear LDS placement
#define DMA16(gp, lp)                                                        \
  __builtin_amdgcn_global_load_lds(                                          \
      (const __attribute__((address_space(1))) uint32_t*)(const void*)(gp),  \
      (__attribute__((address_space(3))) uint32_t*)(void*)(lp), 16, 0, 0)

// belt-and-braces drain before barrier (syncthreads also drains, per m97 asm)
#define WAITVM0() asm volatile("s_waitcnt vmcnt(0)" ::: "memory")

// ---------------- kernel 1a: tokens fp32 -> f16 natural [b][l][d] + transposed [b][d][l]
__global__ __launch_bounds__(256) void k_convert(const float* __restrict__ tok,
                                                 _Float16* __restrict__ T,
                                                 _Float16* __restrict__ TT) {
  __shared__ __align__(16) _Float16 tile[64][68];
  const int b = blockIdx.z;
  const int l0 = blockIdx.y * 64, d0 = blockIdx.x * 64;
  const int tid = threadIdx.x;
  const int rr = tid >> 4;
  const int cq = tid & 15;
  const size_t base = (size_t)b * LN * DN;
#pragma unroll
  for (int p = 0; p < 4; ++p) {
    const int l = p * 16 + rr;
    const float4 v = *(const float4*)(tok + base + (size_t)(l0 + l) * DN + d0 + cq * 4);
    f16x4 hv;
    hv[0] = (_Float16)v.x; hv[1] = (_Float16)v.y; hv[2] = (_Float16)v.z; hv[3] = (_Float16)v.w;
    *(f16x4*)(T + base + (size_t)(l0 + l) * DN + d0 + cq * 4) = hv;
    tile[cq * 4 + 0][l] = hv[0];
    tile[cq * 4 + 1][l] = hv[1];
    tile[cq * 4 + 2][l] = hv[2];
    tile[cq * 4 + 3][l] = hv[3];
  }
  __syncthreads();
  const size_t baseT = (size_t)b * DN * LN;
#pragma unroll
  for (int p = 0; p < 4; ++p) {
    const int d = p * 16 + rr;
    const f16x4 hv = *(const f16x4*)(&tile[d][cq * 4]);
    *(f16x4*)(TT + baseT + (size_t)(d0 + d) * LN + l0 + cq * 4) = hv;
  }
}

// ---------------- kernel 1b: queries fp32 -> f16 + 1/max(||q||,eps)
__global__ __launch_bounds__(256) void k_queries(const float* __restrict__ q,
                                                 _Float16* __restrict__ Qh,
                                                 float* __restrict__ invqn) {
  const int qr = blockIdx.x;
  const int tid = threadIdx.x;
  const float4 v = *(const float4*)(q + (size_t)qr * DN + tid * 4);
  float ss = v.x * v.x + v.y * v.y + v.z * v.z + v.w * v.w;
#pragma unroll
  for (int off = 1; off < 64; off <<= 1) ss += __shfl_xor(ss, off, 64);
  __shared__ float red[4];
  if ((tid & 63) == 0) red[tid >> 6] = ss;
  __syncthreads();
  const float tot = red[0] + red[1] + red[2] + red[3];
  f16x4 hv;
  hv[0] = (_Float16)v.x; hv[1] = (_Float16)v.y; hv[2] = (_Float16)v.z; hv[3] = (_Float16)v.w;
  *(f16x4*)(Qh + (size_t)qr * DN + tid * 4) = hv;
  if (tid == 0) invqn[qr] = 1.0f / fmaxf(sqrtf(tot), 1e-12f);
}

// XCD-locality decode: all 8 q-tile blocks of a given b get linear index
// i == b (mod 8) -> same XCD. Verified r2: FETCH_SIZE 529->77 MB.
__device__ __forceinline__ void decode_bq(int g, int& b, int& q0) {
  const int xcd = g & 7;
  const int t = g >> 3;
  const int qt8 = t & 7;
  b = ((t >> 3) << 3) | xcd;
  q0 = qt8 * 64;
}

// ---------------- kernel 2: scores + exact softmax + num + P (normalized attn, f16)
// 8 waves; wave w owns all 4 q-subtiles x 8 l-tiles (l in [w*128,(w+1)*128)).
// K-loop: 32 steps of k-chunk 32; B(64KB)+A(4KB) per step via global_load_lds
// into double-buffered LDS with a 16B-unit XOR swizzle -> conflict-free
// ds_read_b128. Sync protocol: m99-style — issue s+1 DMAs, compute s,
// __syncthreads (vmcnt(0)+lgkmcnt(0) drain). No manual vmcnt counting
// (r3's raw-asm protocol raced under graph replay).
__global__ __launch_bounds__(512, 2) void k_scores(const _Float16* __restrict__ Qh,
                                                   const _Float16* __restrict__ T,
                                                   _Float16* __restrict__ P,
                                                   float* __restrict__ numv) {
  __shared__ __align__(16) _Float16 Bb[2][32768];  // 2 x 64KB, 16B-swizzled
  __shared__ __align__(16) _Float16 As[2][2048];   // 2 x 4KB
  __shared__ float maxbuf[8][64];
  __shared__ float sumbuf[8][64];
  __shared__ float numbuf[8][64];
  __shared__ float Mbuf[64];
  __shared__ float Rbuf[64];
  int b, q0;
  decode_bq(blockIdx.x, b, q0);
  const int tid = threadIdx.x;
  const int w = tid >> 6, lane = tid & 63, c = lane & 15, quad = lane >> 4;

  const char* __restrict__ gT = (const char*)(T + (size_t)b * LN * DN);
  const char* __restrict__ gA = (const char*)(Qh + (size_t)q0 * DN);

  // per-lane DMA source (inverse of the LDS swizzle): slot = slab*64 + lane
  const int r4 = lane >> 2;                              // row within 16-row slab
  const int qsw = ((lane & 3) - ((lane >> 3) & 3)) & 3;  // source 16B colgroup
  const char* gBbase = gT + (size_t)(w * 128 + r4) * 2048 + qsw * 16;
  const char* gAbase = gA + (size_t)(w * 16 + r4) * 2048 + qsw * 16;  // waves 0..3

  // fragment LDS offsets (f16 units): row*32 + swizzled-colgroup*8
  const int bswz = ((quad + ((c >> 1) & 3)) & 3) * 8;
  const int boff = (w * 128 + c) * 32 + bswz;  // + lt*512
  const int aoff = c * 32 + bswz;              // + qt*512

  f32x4 acc[4][8];
#pragma unroll
  for (int i = 0; i < 4; ++i)
#pragma unroll
    for (int j = 0; j < 8; ++j) acc[i][j] = 0.f;

  // prologue: stage step 0 into buffer 0, full drain
#pragma unroll
  for (int j = 0; j < 8; ++j) DMA16(gBbase + j * 32768, &Bb[0][(w * 8 + j) * 512]);
  if (w < 4) DMA16(gAbase, &As[0][w * 512]);
  WAITVM0();
  __syncthreads();

  for (int s = 0; s < 32; ++s) {
    const int cur = s & 1;
    if (s < 31) {  // issue step s+1 into the other buffer (its previous readers
                   // finished before the barrier that ended iteration s-1)
      const int sn = s + 1;
#pragma unroll
      for (int j = 0; j < 8; ++j)
        DMA16(gBbase + j * 32768 + sn * 64, &Bb[cur ^ 1][(w * 8 + j) * 512]);
      if (w < 4) DMA16(gAbase + sn * 64, &As[cur ^ 1][w * 512]);
    }

    const _Float16* __restrict__ Bp = &Bb[cur][0];
    const _Float16* __restrict__ Ap = &As[cur][0];
    f16x8 afr[4];
#pragma unroll
    for (int qt = 0; qt < 4; ++qt) afr[qt] = *(const f16x8*)(Ap + aoff + qt * 512);
#pragma unroll
    for (int lt = 0; lt < 8; ++lt) {
      const f16x8 bv = *(const f16x8*)(Bp + boff + lt * 512);
#pragma unroll
      for (int qt = 0; qt < 4; ++qt)
        acc[qt][lt] = __builtin_amdgcn_mfma_f32_16x16x32_f16(afr[qt], bv, acc[qt][lt], 0, 0, 0);
    }
    WAITVM0();        // step s+1 DMAs landed (redundant with syncthreads' drain)
    __syncthreads();  // all waves' DMAs + ds_reads complete
  }

  // acc[qt][lt][r] = u  at row q = qt*16+quad*4+r , col l = w*128+lt*16+c
  float mx[4][4];
#pragma unroll
  for (int qt = 0; qt < 4; ++qt)
#pragma unroll
    for (int r = 0; r < 4; ++r) {
      float m = acc[qt][0][r];
#pragma unroll
      for (int lt = 1; lt < 8; ++lt) m = fmaxf(m, acc[qt][lt][r]);
      mx[qt][r] = m;
    }
#pragma unroll
  for (int off = 1; off < 16; off <<= 1)
#pragma unroll
    for (int qt = 0; qt < 4; ++qt)
#pragma unroll
      for (int r = 0; r < 4; ++r) mx[qt][r] = fmaxf(mx[qt][r], __shfl_xor(mx[qt][r], off, 64));
  if (c == 0)
#pragma unroll
    for (int qt = 0; qt < 4; ++qt)
#pragma unroll
      for (int r = 0; r < 4; ++r) maxbuf[w][qt * 16 + quad * 4 + r] = mx[qt][r];
  __syncthreads();
  if (tid < 64) {
    float m = maxbuf[0][tid];
#pragma unroll
    for (int ww = 1; ww < 8; ++ww) m = fmaxf(m, maxbuf[ww][tid]);
    Mbuf[tid] = m;
  }
  __syncthreads();

  const float KE = 0.045084220027780106f;  // log2(e)/32  (scores = u/sqrt(1024))
  float Mr[4][4], sl[4][4], nl[4][4];
#pragma unroll
  for (int qt = 0; qt < 4; ++qt)
#pragma unroll
    for (int r = 0; r < 4; ++r) {
      Mr[qt][r] = Mbuf[qt * 16 + quad * 4 + r];
      sl[qt][r] = 0.f;
      nl[qt][r] = 0.f;
    }
#pragma unroll
  for (int qt = 0; qt < 4; ++qt)
#pragma unroll
    for (int lt = 0; lt < 8; ++lt)
#pragma unroll
      for (int r = 0; r < 4; ++r) {
        const float u = acc[qt][lt][r];
        const float p = exp2f((u - Mr[qt][r]) * KE);
        acc[qt][lt][r] = p;
        sl[qt][r] += p;
        nl[qt][r] += p * u;
      }
#pragma unroll
  for (int off = 1; off < 16; off <<= 1)
#pragma unroll
    for (int qt = 0; qt < 4; ++qt)
#pragma unroll
      for (int r = 0; r < 4; ++r) {
        sl[qt][r] += __shfl_xor(sl[qt][r], off, 64);
        nl[qt][r] += __shfl_xor(nl[qt][r], off, 64);
      }
  if (c == 0)
#pragma unroll
    for (int qt = 0; qt < 4; ++qt)
#pragma unroll
      for (int r = 0; r < 4; ++r) {
        sumbuf[w][qt * 16 + quad * 4 + r] = sl[qt][r];
        numbuf[w][qt * 16 + quad * 4 + r] = nl[qt][r];
      }
  __syncthreads();
  if (tid < 64) {
    float S = 0.f, N = 0.f;
#pragma unroll
    for (int ww = 0; ww < 8; ++ww) {
      S += sumbuf[ww][tid];
      N += numbuf[ww][tid];
    }
    Rbuf[tid] = 1.0f / S;
    numv[(size_t)b * QN + q0 + tid] = N / S;  // = q . agg  (exact fp32 ratio)
  }
  __syncthreads();

  _Float16* Pb = P + ((size_t)b * QN + q0) * LN;
#pragma unroll
  for (int qt = 0; qt < 4; ++qt)
#pragma unroll
    for (int r = 0; r < 4; ++r) {
      const int row = qt * 16 + quad * 4 + r;
      const float rS = Rbuf[row];
      _Float16* prow = Pb + (size_t)row * LN + c;
#pragma unroll
      for (int lt = 0; lt < 8; ++lt) prow[w * 128 + lt * 16] = (_Float16)(acc[qt][lt][r] * rS);
    }
}

// ---------------- kernel 3: agg = P @ T (via TT), reduce to ||agg||^2 per (b,q)
// identical pipeline; B rows = d (from TT), A rows = q (from P), k = l
__global__ __launch_bounds__(512, 2) void k_agg(const _Float16* __restrict__ P,
                                                const _Float16* __restrict__ TT,
                                                float* __restrict__ norm2) {
  __shared__ __align__(16) _Float16 Bb[2][32768];
  __shared__ __align__(16) _Float16 As[2][2048];
  __shared__ float redbuf[8][64];
  int b, q0;
  decode_bq(blockIdx.x, b, q0);
  const int tid = threadIdx.x;
  const int w = tid >> 6, lane = tid & 63, c = lane & 15, quad = lane >> 4;

  const char* __restrict__ gT = (const char*)(TT + (size_t)b * DN * LN);
  const char* __restrict__ gA = (const char*)(P + ((size_t)b * QN + q0) * LN);

  const int r4 = lane >> 2;
  const int qsw = ((lane & 3) - ((lane >> 3) & 3)) & 3;
  const char* gBbase = gT + (size_t)(w * 128 + r4) * 2048 + qsw * 16;
  const char* gAbase = gA + (size_t)(w * 16 + r4) * 2048 + qsw * 16;

  const int bswz = ((quad + ((c >> 1) & 3)) & 3) * 8;
  const int boff = (w * 128 + c) * 32 + bswz;
  const int aoff = c * 32 + bswz;

  f32x4 acc[4][8];
#pragma unroll
  for (int i = 0; i < 4; ++i)
#pragma unroll
    for (int j = 0; j < 8; ++j) acc[i][j] = 0.f;

#pragma unroll
  for (int j = 0; j < 8; ++j) DMA16(gBbase + j * 32768, &Bb[0][(w * 8 + j) * 512]);
  if (w < 4) DMA16(gAbase, &As[0][w * 512]);
  WAITVM0();
  __syncthreads();

  for (int s = 0; s < 32; ++s) {
    const int cur = s & 1;
    if (s < 31) {
      const int sn = s + 1;
#pragma unroll
      for (int j = 0; j < 8; ++j)
        DMA16(gBbase + j * 32768 + sn * 64, &Bb[cur ^ 1][(w * 8 + j) * 512]);
      if (w < 4) DMA16(gAbase + sn * 64, &As[cur ^ 1][w * 512]);
    }

    const _Float16* __restrict__ Bp = &Bb[cur][0];
    const _Float16* __restrict__ Ap = &As[cur][0];
    f16x8 afr[4];
#pragma unroll
    for (int qt = 0; qt < 4; ++qt) afr[qt] = *(const f16x8*)(Ap + aoff + qt * 512);
#pragma unroll
    for (int dt = 0; dt < 8; ++dt) {
      const f16x8 bv = *(const f16x8*)(Bp + boff + dt * 512);
#pragma unroll
      for (int qt = 0; qt < 4; ++qt)
        acc[qt][dt] = __builtin_amdgcn_mfma_f32_16x16x32_f16(afr[qt], bv, acc[qt][dt], 0, 0, 0);
    }
    WAITVM0();
    __syncthreads();
  }

  float ss[4][4];
#pragma unroll
  for (int qt = 0; qt < 4; ++qt)
#pragma unroll
    for (int r = 0; r < 4; ++r) {
      float s = 0.f;
#pragma unroll
      for (int dt = 0; dt < 8; ++dt) {
        const float v = acc[qt][dt][r];
        s += v * v;
      }
      ss[qt][r] = s;
    }
#pragma unroll
  for (int off = 1; off < 16; off <<= 1)
#pragma unroll
    for (int qt = 0; qt < 4; ++qt)
#pragma unroll
      for (int r = 0; r < 4; ++r) ss[qt][r] += __shfl_xor(ss[qt][r], off, 64);
  if (c == 0)
#pragma unroll
    for (int qt = 0; qt < 4; ++qt)
#pragma unroll
      for (int r = 0; r < 4; ++r) redbuf[w][qt * 16 + quad * 4 + r] = ss[qt][r];
  __syncthreads();
  if (tid < 64) {
    float s = 0.f;
#pragma unroll
    for (int ww = 0; ww < 8; ++ww) s += redbuf[ww][tid];
    norm2[(size_t)b * QN + q0 + tid] = s;
  }
}

// ---------------- kernel 4: logits[q][b] = num * invqn / max(||agg||, eps)
__global__ __launch_bounds__(256) void k_final(const float* __restrict__ numv,
                                               const float* __restrict__ norm2,
                                               const float* __restrict__ invqn,
                                               float* __restrict__ out) {
  const int idx = blockIdx.x * 256 + threadIdx.x;  // 0..32767
  const int q = idx >> 6, b = idx & 63;
  const float n = numv[(size_t)b * QN + q];
  const float d = sqrtf(norm2[(size_t)b * QN + q]);
  out[idx] = n * invqn[q] / fmaxf(d, 1e-12f);
}

extern "C" void kernel_launch(void* const* d_in, const int* in_sizes, int n_in,
                              void* d_out, int out_size, void* d_ws, size_t ws_size,
                              hipStream_t stream) {
  (void)in_sizes; (void)n_in; (void)out_size; (void)ws_size;
  const float* queries = (const float*)d_in[0];
  const float* tok = (const float*)d_in[1];
  float* out = (float*)d_out;
  char* ws = (char*)d_ws;

  // workspace layout (bytes)
  _Float16* TT = (_Float16*)(ws + 0);           // 128 MB  [b][d][l]
  _Float16* T = (_Float16*)(ws + 134217728);    // 128 MB  [b][l][d]
  _Float16* P = (_Float16*)(ws + 268435456);    // 64 MB   [b][q][l]
  _Float16* Qh = (_Float16*)(ws + 335544320);   // 1 MB    [q][d]
  float* invqn = (float*)(ws + 336592896);      // 2 KB
  float* numv = (float*)(ws + 336594944);       // 128 KB  [b][q]
  float* norm2 = (float*)(ws + 336726016);      // 128 KB  [b][q]

  hipLaunchKernelGGL(k_convert, dim3(16, 16, 64), dim3(256), 0, stream, tok, T, TT);
  hipLaunchKernelGGL(k_queries, dim3(512), dim3(256), 0, stream, queries, Qh, invqn);
  hipLaunchKernelGGL(k_scores, dim3(512), dim3(512), 0, stream, Qh, T, P, numv);
  hipLaunchKernelGGL(k_agg, dim3(512), dim3(512), 0, stream, P, TT, norm2);
  hipLaunchKernelGGL(k_final, dim3(128), dim3(256), 0, stream, numv, norm2, invqn, out);
}